// Round 7
// baseline (47.465 us; speedup 1.0000x reference)
//
#include <hip/hip_runtime.h>
#include <stdint.h>

// BERT input representation, round 7: persistent pipelined streamer.
//   out[r][c] = x'[r] @ W[:,c] + pe2[r&511][c]
//   x'  = x + broadcast(seg-reduce x)   (seg commutes through the GEMM)
//   pe2 = PE + b_emb*(1+Sw) + b_seg     (2 MB, L2-resident)
// R1-R6 evidence: store pattern + epilogue VALU don't matter; all one-shot
// block designs stall at ~4 TB/s vs fillBuffer's 6.5. This round: persistent
// blocks (1024, 4/CU, 16 waves/CU), W-frags register-resident across a 4-tile
// loop, 1-deep pipeline (prefetch next x'-frags before current epilogue),
// NONTEMPORAL output stores (output is write-once; keep it out of L2).
//
// d_ws: [0,128KB) W bf16 A-frag | [128KB,+2MB) pe2 f32 | [+2MB,+4MB) x' bf16

typedef __attribute__((ext_vector_type(8))) short short8;
typedef __attribute__((ext_vector_type(4))) float f32x4;
typedef __attribute__((ext_vector_type(4))) unsigned short u16x4;

#define D_DIM 1024
#define WS_PE_OFF 131072
#define WS_X_OFF (131072 + 2097152)

__device__ __forceinline__ unsigned short f2bf(float f) {
  unsigned u = __float_as_uint(f);
  u = (u + 0x7FFFu + ((u >> 16) & 1u)) >> 16;  // RNE f32 -> bf16
  return (unsigned short)u;
}

__global__ __launch_bounds__(256) void bert_setup(
    const float* __restrict__ x, const float* __restrict__ W,
    const float* __restrict__ b_emb, const float* __restrict__ w_seg,
    const float* __restrict__ b_seg, unsigned short* __restrict__ wsW,
    float* __restrict__ wsPE, unsigned short* __restrict__ wsX) {
  const int bid = blockIdx.x;
  const int tid = threadIdx.x;
  if (bid < 1024) {
    // ---- x' = x + seg broadcast; one wave per 8-row segment group ----
    const int lane = tid & 63;
    const int gg = bid * 4 + (tid >> 6);  // group 0..4095
    const size_t base = (size_t)gg * 512; // 8 rows x 64 f32, contiguous
    const int sl = lane >> 4;             // this lane's rows: sl and sl+4
    const int c0 = (lane & 15) * 4;       // this lane's 4 cols
    const float4 v1 = *reinterpret_cast<const float4*>(x + base + lane * 4);
    const float4 v2 = *reinterpret_cast<const float4*>(x + base + 256 + lane * 4);
    const float wa = w_seg[sl], wb = w_seg[sl + 4];
    float q0 = wa * v1.x + wb * v2.x;
    float q1 = wa * v1.y + wb * v2.y;
    float q2 = wa * v1.z + wb * v2.z;
    float q3 = wa * v1.w + wb * v2.w;
    q0 += __shfl_xor(q0, 16); q1 += __shfl_xor(q1, 16);
    q2 += __shfl_xor(q2, 16); q3 += __shfl_xor(q3, 16);
    q0 += __shfl_xor(q0, 32); q1 += __shfl_xor(q1, 32);
    q2 += __shfl_xor(q2, 32); q3 += __shfl_xor(q3, 32);
    u16x4 o1, o2;
    o1[0] = f2bf(v1.x + q0); o1[1] = f2bf(v1.y + q1);
    o1[2] = f2bf(v1.z + q2); o1[3] = f2bf(v1.w + q3);
    o2[0] = f2bf(v2.x + q0); o2[1] = f2bf(v2.y + q1);
    o2[2] = f2bf(v2.z + q2); o2[3] = f2bf(v2.w + q3);
    *reinterpret_cast<u16x4*>(wsX + base + sl * 64 + c0) = o1;
    *reinterpret_cast<u16x4*>(wsX + base + (sl + 4) * 64 + c0) = o2;
  } else if (bid < 1536) {
    // ---- pe2[s][c] = PE + b_emb[c]*(1+Sw) + b_seg ----
    const int t = (bid - 1024) * 256 + tid;
    const int s = t >> 8;
    const int c0 = (t & 255) * 4;
    float Sw = 0.f;
#pragma unroll
    for (int i = 0; i < 8; ++i) Sw += w_seg[i];
    const float inv2pi = 0.15915494309189535f;
    const float KLOG = 0.02595256324130752f;  // log2(10000)/512
    const float d0 = exp2f(-(float)(c0 >> 1) * KLOG) * inv2pi;
    const float d1 = exp2f(-(float)((c0 >> 1) + 1) * KLOG) * inv2pi;
    const float fs = (float)s;
    const float4 eb = *reinterpret_cast<const float4*>(b_emb + c0);
    const float cb = b_seg[0];
    float4 pv;
    pv.x = __builtin_amdgcn_sinf(__builtin_amdgcn_fractf(fs * d0)) + eb.x * (1.f + Sw) + cb;
    pv.y = __builtin_amdgcn_sinf(__builtin_amdgcn_fractf(fs * d0 + 0.25f)) + eb.y * (1.f + Sw) + cb;
    pv.z = __builtin_amdgcn_sinf(__builtin_amdgcn_fractf(fs * d1)) + eb.z * (1.f + Sw) + cb;
    pv.w = __builtin_amdgcn_sinf(__builtin_amdgcn_fractf(fs * d1 + 0.25f)) + eb.w * (1.f + Sw) + cb;
    *reinterpret_cast<float4*>(wsPE + (size_t)t * 4) = pv;
  } else {
    // ---- W -> bf16 A-fragment layout (verified rounds 2/4/5/6) ----
    const int t = (bid - 1536) * 256 + tid;  // 0..8191
    const int cfg = t >> 7;
    const int kf = (t >> 6) & 1;
    const int lane = t & 63;
    const int col = cfg * 16 + (lane & 15);
    const int k0 = kf * 32 + ((lane >> 4) << 3);
    short8 o;
#pragma unroll
    for (int i = 0; i < 8; ++i)
      o[i] = (short)f2bf(W[(size_t)(k0 + i) * D_DIM + col]);
    *reinterpret_cast<short8*>(wsW + (size_t)t * 8) = o;
  }
}

#define ITERS 4

__global__ __launch_bounds__(256, 4) void bert_main(
    const unsigned short* __restrict__ wsX,
    const unsigned short* __restrict__ wsW, const float* __restrict__ wsPE,
    float* __restrict__ out) {
  const int tid = threadIdx.x;
  const int lane = tid & 63;
  const int w = tid >> 6;  // wave 0..3
  const int bid = blockIdx.x;
  const int colq = bid >> 8;  // 0..3: 256-col quarter (bid%8 == jj%8 -> the 4
  const int jj = bid & 255;   // col-quarters of a row range share an XCD)
  const int colbase = colq * 256 + w * 64;
  const int L15 = lane & 15;
  const int g = lane >> 4;

  // ---- A fragments: this wave's 64 W-cols, register-resident all kernel ----
  short8 aW[4][2];
#pragma unroll
  for (int cf = 0; cf < 4; ++cf)
#pragma unroll
    for (int kf = 0; kf < 2; ++kf)
      aW[cf][kf] = *reinterpret_cast<const short8*>(
          wsW + ((size_t)(((colbase >> 4) + cf) * 2 + kf) * 64 + lane) * 8);

  // ---- 4 row-tiles of 32 rows, 1-deep pipelined ----
  int rbase = jj * 128;
  short8 bX[2][2];
#pragma unroll
  for (int rf = 0; rf < 2; ++rf)
#pragma unroll
    for (int kf = 0; kf < 2; ++kf)
      bX[rf][kf] = *reinterpret_cast<const short8*>(
          wsX + (size_t)(rbase + rf * 16 + L15) * 64 + kf * 32 + g * 8);

#pragma unroll
  for (int it = 0; it < ITERS; ++it) {
    // MFMA for current tile
    f32x4 acc[4][2];
#pragma unroll
    for (int cf = 0; cf < 4; ++cf)
#pragma unroll
      for (int rf = 0; rf < 2; ++rf) {
        f32x4 c = {0.f, 0.f, 0.f, 0.f};
        c = __builtin_amdgcn_mfma_f32_16x16x32_bf16(aW[cf][0], bX[rf][0], c, 0, 0, 0);
        c = __builtin_amdgcn_mfma_f32_16x16x32_bf16(aW[cf][1], bX[rf][1], c, 0, 0, 0);
        acc[cf][rf] = c;
      }

    // prefetch next tile's x'-frags (issues before the store burst)
    short8 bN[2][2];
    if (it + 1 < ITERS) {
#pragma unroll
      for (int rf = 0; rf < 2; ++rf)
#pragma unroll
        for (int kf = 0; kf < 2; ++kf)
          bN[rf][kf] = *reinterpret_cast<const short8*>(
              wsX + (size_t)(rbase + 32 + rf * 16 + L15) * 64 + kf * 32 + g * 8);
    }

    // epilogue: pe2 (L2-hit) + add + NONTEMPORAL store
#pragma unroll
    for (int cf = 0; cf < 4; ++cf) {
      const int colf = colbase + cf * 16 + g * 4;
#pragma unroll
      for (int rf = 0; rf < 2; ++rf) {
        const int row = rbase + rf * 16 + L15;
        const f32x4 pe = *reinterpret_cast<const f32x4*>(
            wsPE + (size_t)(row & 511) * D_DIM + colf);
        f32x4 o = acc[cf][rf] + pe;
        __builtin_nontemporal_store(
            o, reinterpret_cast<f32x4*>(out + (size_t)row * D_DIM + colf));
      }
    }

    if (it + 1 < ITERS) {
#pragma unroll
      for (int rf = 0; rf < 2; ++rf)
#pragma unroll
        for (int kf = 0; kf < 2; ++kf) bX[rf][kf] = bN[rf][kf];
    }
    rbase += 32;
  }
}

extern "C" void kernel_launch(void* const* d_in, const int* in_sizes, int n_in,
                              void* d_out, int out_size, void* d_ws,
                              size_t ws_size, hipStream_t stream) {
  const float* x = (const float*)d_in[0];
  const float* W = (const float*)d_in[1];
  const float* b_emb = (const float*)d_in[2];
  const float* w_seg = (const float*)d_in[3];
  const float* b_seg = (const float*)d_in[4];
  float* out = (float*)d_out;

  unsigned short* wsW = (unsigned short*)d_ws;                      // 128 KB
  float* wsPE = (float*)((char*)d_ws + WS_PE_OFF);                  // 2 MB
  unsigned short* wsX = (unsigned short*)((char*)d_ws + WS_X_OFF);  // 4 MB

  bert_setup<<<1568, 256, 0, stream>>>(x, W, b_emb, w_seg, b_seg, wsW, wsPE, wsX);
  bert_main<<<1024, 256, 0, stream>>>(wsX, wsW, wsPE, out);
}

// Round 8
// 47.332 us; speedup vs baseline: 1.0028x; 1.0028x over previous
//
#include <hip/hip_runtime.h>
#include <stdint.h>

// BERT input representation, round 8: dense contiguous write footprint.
//   out[r][c] = x'[r] @ W[:,c] + pe2[r&511][c]
//   x'  = x + broadcast(seg-reduce x)   (seg commutes through the GEMM)
//   pe2 = PE + b_emb*(1+Sw) + b_seg     (2 MB, L2-resident)
// R1-R7: per-instr store coalescing, epilogue VALU, persistence, nt-stores all
// failed to move the ~36us main floor (~4 TB/s vs fillBuffer 6.5). The one
// untested variable: each block's WRITE FOOTPRINT was a sparse column slice,
// so every DRAM row was activated by 4-8 different blocks. This round each
// block owns 16 FULL rows = one dense contiguous 64KB region written once.
// 2048 blocks x 256 thr, no LDS, no barriers; wave = 256 cols; col-chunk loop
// keeps registers low and interleaves MFMA with stores.
//
// d_ws: [0,128KB) W bf16 A-frag | [128KB,+2MB) pe2 f32 | [+2MB,+4MB) x' bf16

typedef __attribute__((ext_vector_type(8))) short short8;
typedef __attribute__((ext_vector_type(4))) float f32x4;
typedef __attribute__((ext_vector_type(4))) unsigned short u16x4;

#define D_DIM 1024
#define WS_PE_OFF 131072
#define WS_X_OFF (131072 + 2097152)

__device__ __forceinline__ unsigned short f2bf(float f) {
  unsigned u = __float_as_uint(f);
  u = (u + 0x7FFFu + ((u >> 16) & 1u)) >> 16;  // RNE f32 -> bf16
  return (unsigned short)u;
}

__global__ __launch_bounds__(256) void bert_setup(
    const float* __restrict__ x, const float* __restrict__ W,
    const float* __restrict__ b_emb, const float* __restrict__ w_seg,
    const float* __restrict__ b_seg, unsigned short* __restrict__ wsW,
    float* __restrict__ wsPE, unsigned short* __restrict__ wsX) {
  const int bid = blockIdx.x;
  const int tid = threadIdx.x;
  if (bid < 1024) {
    // ---- x' = x + seg broadcast; one wave per 8-row segment group ----
    const int lane = tid & 63;
    const int gg = bid * 4 + (tid >> 6);  // group 0..4095
    const size_t base = (size_t)gg * 512; // 8 rows x 64 f32, contiguous
    const int sl = lane >> 4;             // this lane's rows: sl and sl+4
    const int c0 = (lane & 15) * 4;       // this lane's 4 cols
    const float4 v1 = *reinterpret_cast<const float4*>(x + base + lane * 4);
    const float4 v2 = *reinterpret_cast<const float4*>(x + base + 256 + lane * 4);
    const float wa = w_seg[sl], wb = w_seg[sl + 4];
    float q0 = wa * v1.x + wb * v2.x;
    float q1 = wa * v1.y + wb * v2.y;
    float q2 = wa * v1.z + wb * v2.z;
    float q3 = wa * v1.w + wb * v2.w;
    q0 += __shfl_xor(q0, 16); q1 += __shfl_xor(q1, 16);
    q2 += __shfl_xor(q2, 16); q3 += __shfl_xor(q3, 16);
    q0 += __shfl_xor(q0, 32); q1 += __shfl_xor(q1, 32);
    q2 += __shfl_xor(q2, 32); q3 += __shfl_xor(q3, 32);
    u16x4 o1, o2;
    o1[0] = f2bf(v1.x + q0); o1[1] = f2bf(v1.y + q1);
    o1[2] = f2bf(v1.z + q2); o1[3] = f2bf(v1.w + q3);
    o2[0] = f2bf(v2.x + q0); o2[1] = f2bf(v2.y + q1);
    o2[2] = f2bf(v2.z + q2); o2[3] = f2bf(v2.w + q3);
    *reinterpret_cast<u16x4*>(wsX + base + sl * 64 + c0) = o1;
    *reinterpret_cast<u16x4*>(wsX + base + (sl + 4) * 64 + c0) = o2;
  } else if (bid < 1536) {
    // ---- pe2[s][c] = PE + b_emb[c]*(1+Sw) + b_seg ----
    const int t = (bid - 1024) * 256 + tid;
    const int s = t >> 8;
    const int c0 = (t & 255) * 4;
    float Sw = 0.f;
#pragma unroll
    for (int i = 0; i < 8; ++i) Sw += w_seg[i];
    const float inv2pi = 0.15915494309189535f;
    const float KLOG = 0.02595256324130752f;  // log2(10000)/512
    const float d0 = exp2f(-(float)(c0 >> 1) * KLOG) * inv2pi;
    const float d1 = exp2f(-(float)((c0 >> 1) + 1) * KLOG) * inv2pi;
    const float fs = (float)s;
    const float4 eb = *reinterpret_cast<const float4*>(b_emb + c0);
    const float cb = b_seg[0];
    float4 pv;
    pv.x = __builtin_amdgcn_sinf(__builtin_amdgcn_fractf(fs * d0)) + eb.x * (1.f + Sw) + cb;
    pv.y = __builtin_amdgcn_sinf(__builtin_amdgcn_fractf(fs * d0 + 0.25f)) + eb.y * (1.f + Sw) + cb;
    pv.z = __builtin_amdgcn_sinf(__builtin_amdgcn_fractf(fs * d1)) + eb.z * (1.f + Sw) + cb;
    pv.w = __builtin_amdgcn_sinf(__builtin_amdgcn_fractf(fs * d1 + 0.25f)) + eb.w * (1.f + Sw) + cb;
    *reinterpret_cast<float4*>(wsPE + (size_t)t * 4) = pv;
  } else {
    // ---- W -> bf16 A-fragment layout (verified rounds 2/4/5/6/7) ----
    const int t = (bid - 1536) * 256 + tid;  // 0..8191
    const int cfg = t >> 7;
    const int kf = (t >> 6) & 1;
    const int lane = t & 63;
    const int col = cfg * 16 + (lane & 15);
    const int k0 = kf * 32 + ((lane >> 4) << 3);
    short8 o;
#pragma unroll
    for (int i = 0; i < 8; ++i)
      o[i] = (short)f2bf(W[(size_t)(k0 + i) * D_DIM + col]);
    *reinterpret_cast<short8*>(wsW + (size_t)t * 8) = o;
  }
}

__global__ __launch_bounds__(256) void bert_main(
    const unsigned short* __restrict__ wsX,
    const unsigned short* __restrict__ wsW, const float* __restrict__ wsPE,
    float* __restrict__ out) {
  const int tid = threadIdx.x;
  const int lane = tid & 63;
  const int w = tid >> 6;         // wave 0..3 -> 256-col slice
  const int rbase = blockIdx.x * 16;  // block owns rows rbase..rbase+15:
                                      // one dense contiguous 64KB out region
  const int L15 = lane & 15;
  const int g = lane >> 4;
  const int row = rbase + L15;
  const int prow = row & 511;

  // ---- B fragments: this wave's 16 x'-rows, register-resident ----
  short8 bX[2];
#pragma unroll
  for (int kf = 0; kf < 2; ++kf)
    bX[kf] = *reinterpret_cast<const short8*>(
        wsX + (size_t)row * 64 + kf * 32 + g * 8);

  const float* peRow = wsPE + (size_t)prow * D_DIM;
  float* outRow = out + (size_t)row * D_DIM;

  // ---- col-chunk loop: 4 x 64 cols; MFMA batches interleave with stores ----
#pragma unroll
  for (int cc = 0; cc < 4; ++cc) {
    const int cfg0 = w * 16 + cc * 4;  // global 16-col fragment index base

    short8 aW[4][2];
#pragma unroll
    for (int cf = 0; cf < 4; ++cf)
#pragma unroll
      for (int kf = 0; kf < 2; ++kf)
        aW[cf][kf] = *reinterpret_cast<const short8*>(
            wsW + ((size_t)((cfg0 + cf) * 2 + kf) * 64 + lane) * 8);

    f32x4 acc[4];
#pragma unroll
    for (int cf = 0; cf < 4; ++cf) {
      f32x4 c = {0.f, 0.f, 0.f, 0.f};
      c = __builtin_amdgcn_mfma_f32_16x16x32_bf16(aW[cf][0], bX[0], c, 0, 0, 0);
      c = __builtin_amdgcn_mfma_f32_16x16x32_bf16(aW[cf][1], bX[1], c, 0, 0, 0);
      acc[cf] = c;
    }

#pragma unroll
    for (int cf = 0; cf < 4; ++cf) {
      const int colf = (cfg0 + cf) * 16 + g * 4;
      const f32x4 pe = *reinterpret_cast<const f32x4*>(peRow + colf);
      const f32x4 o = acc[cf] + pe;
      *reinterpret_cast<f32x4*>(outRow + colf) = o;
    }
  }
}

extern "C" void kernel_launch(void* const* d_in, const int* in_sizes, int n_in,
                              void* d_out, int out_size, void* d_ws,
                              size_t ws_size, hipStream_t stream) {
  const float* x = (const float*)d_in[0];
  const float* W = (const float*)d_in[1];
  const float* b_emb = (const float*)d_in[2];
  const float* w_seg = (const float*)d_in[3];
  const float* b_seg = (const float*)d_in[4];
  float* out = (float*)d_out;

  unsigned short* wsW = (unsigned short*)d_ws;                      // 128 KB
  float* wsPE = (float*)((char*)d_ws + WS_PE_OFF);                  // 2 MB
  unsigned short* wsX = (unsigned short*)((char*)d_ws + WS_X_OFF);  // 4 MB

  bert_setup<<<1568, 256, 0, stream>>>(x, W, b_emb, w_seg, b_seg, wsW, wsPE, wsX);
  bert_main<<<2048, 256, 0, stream>>>(wsX, wsW, wsPE, out);
}